// Round 2
// baseline (355.081 us; speedup 1.0000x reference)
//
#include <hip/hip_runtime.h>
#include <stdint.h>

// Problem constants (fp32 in, fp32 out; bf16 MFMA internally)
#define M_ROWS (4*128*512)   // 262144 flattened (b,s,n) rows
#define FDIM 362
#define KSTEPS 12            // K padded to 384 = 12*32 (bf16 MFMA k-step)
#define BM 32                // rows per tile
#define GRID 1024
#define TPB 8                // tiles per block: 1024*8*32 = 262144 rows
#define LROW 768             // LDS bytes per row: 384 bf16 (48 x 16B chunks)
#define G_PER_TILE (BM*181)  // 5792 float2 groups per tile
#define OUT_HALF 16777216    // M_ROWS*64 floats

typedef __attribute__((ext_vector_type(8))) short bf16x8;
typedef __attribute__((ext_vector_type(4))) float f32x4;

__device__ __forceinline__ unsigned short f2bf(float f) {
  union { float f; unsigned int i; } c; c.f = f;
  unsigned int u = c.i;
  u += 0x7FFFu + ((u >> 16) & 1u);   // round-to-nearest-even
  return (unsigned short)(u >> 16);
}

__global__ __launch_bounds__(256, 2) void dfl_kernel(
    const float* __restrict__ x,
    const float* __restrict__ Wg,
    const float* __restrict__ Wgb,
    const float* __restrict__ Wh,
    const float* __restrict__ Whb,
    float* __restrict__ out)
{
  // LDS: double-buffered bf16 A tile [32 rows][768 B] + correction coeffs
  __shared__ __attribute__((aligned(16))) unsigned char Ab[2][BM*LROW]; // 48 KiB
  __shared__ float2 CL[2][BM];                                          // 512 B

  const int tid  = threadIdx.x;
  const int lane = tid & 63;
  const int wv   = tid >> 6;      // 4 waves; wave = one 32-col slab
  const int q    = lane >> 4;
  const int l15  = lane & 15;
  const bool is_h = wv >= 2;
  const float* Wsel  = is_h ? Wh  : Wg;
  const float* Wbsel = is_h ? Whb : Wgb;

  // ---- W fragment preload (fp32 -> bf16 regs, once per block) ----
  // B-frag (16x16x32): lane holds B[k=(lane>>4)*8+j][n=lane&15] = W[d][f],
  // f contiguous => straight reads from row-major W.
  bf16x8 bw[2][KSTEPS];
  float biasf[2], w0f[2];
#pragma unroll
  for (int f = 0; f < 2; ++f) {
    const int dloc = wv*32 + f*16 + l15 - (is_h ? 64 : 0);  // 0..63
    const float* wrow = Wsel + (size_t)dloc * FDIM;
    biasf[f] = Wbsel[dloc];
    w0f[f]   = wrow[0];
#pragma unroll
    for (int k = 0; k < KSTEPS; ++k) {
      union { short s[8]; bf16x8 v; } tmp;
#pragma unroll
      for (int j = 0; j < 8; ++j) {
        const int fi = k*32 + q*8 + j;
        tmp.s[j] = (fi < FDIM) ? (short)f2bf(wrow[fi]) : (short)0;
      }
      bw[f][k] = tmp.v;
    }
  }

  // ---- pre-zero both A buffers (K-pad slots are never rewritten) ----
  {
    f32x4 z = {0.f,0.f,0.f,0.f};
    unsigned char* b0 = &Ab[0][0];
    for (int j = tid; j < 2*BM*LROW/16; j += 256)
      *(f32x4*)(b0 + j*16) = z;
  }
  __syncthreads();

  // ---- staging: fp32 global -> bf16 LDS (write-side XOR swizzle) ----
  // 16B chunk s of row r holds bf16 elements [8s,8s+8) XOR-placed: slot = s^(r&7).
  auto stage = [&](int tile, int p) {
    const int m0 = tile * BM;
    // rank-1 correction coefficients (fp32)
    float rs = 0.f, rp = 0.f;
    const int crow = wv*8 + (lane & 7);
    if (lane < 8) {
      const int gm = m0 + crow;
      rs = x[(size_t)gm * FDIM];           // r_self  (feature 0)
      rp = x[(size_t)(gm ^ 512) * FDIM];   // r_partner (pair row, s-bit flip)
    }
    unsigned char* basep = &Ab[p][0];
#pragma unroll
    for (int it = 0; it < 23; ++it) {
      const int g = it*256 + tid;
      if (g < G_PER_TILE) {
        const int row = (g * 11587) >> 21;     // g/181 (exact for g<5888)
        const int c2  = g - row*181;           // float2 index in row
        const float2 fv = *(const float2*)(x + (size_t)(m0 + row)*FDIM + 2*c2);
        const unsigned int pk =
            ((unsigned int)f2bf(fv.y) << 16) | (unsigned int)f2bf(fv.x);
        const int boff = row*LROW + ((((c2 >> 2) ^ (row & 7))) << 4) + ((c2 & 3) << 2);
        *(unsigned int*)(basep + boff) = pk;
      }
    }
    if (lane < 8)
      CL[p][crow] = make_float2((rp - rs)*0.5f, -(rs + rp)*0.5f);
  };

  stage((int)blockIdx.x, 0);
  __syncthreads();

  for (int i = 0; i < TPB; ++i) {
    const int p = i & 1;
    if (i + 1 < TPB) stage((int)blockIdx.x + (i+1)*GRID, p ^ 1); // loads first

    const int m0 = ((int)blockIdx.x + i*GRID) * BM;
    f32x4 acc[2][2] = {};
    const unsigned char* Abp = &Ab[p][0];
    const int row0 = l15;          // A-frag row = lane&15
    const int row1 = l15 + 16;
    const int sw   = l15 & 7;      // == row1 & 7

#pragma unroll
    for (int k = 0; k < KSTEPS; ++k) {
      const int c = k*4 + q;
      bf16x8 a0 = *(const bf16x8*)(Abp + row0*LROW + ((c ^ sw) << 4));
      bf16x8 a1 = *(const bf16x8*)(Abp + row1*LROW + ((c ^ sw) << 4));
      acc[0][0] = __builtin_amdgcn_mfma_f32_16x16x32_bf16(a0, bw[0][k], acc[0][0], 0,0,0);
      acc[0][1] = __builtin_amdgcn_mfma_f32_16x16x32_bf16(a0, bw[1][k], acc[0][1], 0,0,0);
      acc[1][0] = __builtin_amdgcn_mfma_f32_16x16x32_bf16(a1, bw[0][k], acc[1][0], 0,0,0);
      acc[1][1] = __builtin_amdgcn_mfma_f32_16x16x32_bf16(a1, bw[1][k], acc[1][1], 0,0,0);
    }

    // ---- epilogue: bias + rank-1 feature-0 correction, fp32 stores ----
    float* outp = out + (is_h ? OUT_HALF : 0);
    const int colb = (wv & 1) * 32;
#pragma unroll
    for (int fm = 0; fm < 2; ++fm) {
#pragma unroll
      for (int jj = 0; jj < 4; ++jj) {
        const int rl = fm*16 + q*4 + jj;       // C/D: row=(lane>>4)*4+reg
        const float2 cc2 = CL[p][rl];
        const float cc = is_h ? cc2.y : cc2.x;
        const size_t ob = (size_t)(m0 + rl) * 64;
#pragma unroll
        for (int fn = 0; fn < 2; ++fn) {
          outp[ob + (size_t)(colb + fn*16 + l15)] =
              acc[fm][fn][jj] + biasf[fn] + cc * w0f[fn];
        }
      }
    }
    __syncthreads();  // buf p reads done; stage(i+1) ds_writes visible next iter
  }
}

extern "C" void kernel_launch(void* const* d_in, const int* in_sizes, int n_in,
                              void* d_out, int out_size, void* d_ws, size_t ws_size,
                              hipStream_t stream) {
  (void)in_sizes; (void)n_in; (void)d_ws; (void)ws_size; (void)out_size;
  const float* x   = (const float*)d_in[0];
  const float* Wg  = (const float*)d_in[1];
  const float* Wgb = (const float*)d_in[2];
  const float* Wh  = (const float*)d_in[3];
  const float* Whb = (const float*)d_in[4];
  float* out = (float*)d_out;
  dfl_kernel<<<GRID, 256, 0, stream>>>(x, Wg, Wgb, Wh, Whb, out);
}

// Round 3
// 153.425 us; speedup vs baseline: 2.3144x; 2.3144x over previous
//
#include <hip/hip_runtime.h>
#include <stdint.h>

// fp32 in / fp32 out; bf16 MFMA internally (threshold 6.6e-2 >> bf16 quant err)
#define M_ROWS (4*128*512)   // 262144 flattened (b,s,n) rows
#define FDIM 362
#define KSTEPS 12            // K padded to 384 = 12*32
#define TROWS 16             // rows per tile (one 16x16x32 A-frag)
#define GRID 1024
#define TPB 16               // 1024*16*16 = 262144 rows
#define OUT_HALF 16777216    // M_ROWS*64

typedef __attribute__((ext_vector_type(8))) short bf16x8;
typedef __attribute__((ext_vector_type(4))) float f32x4;

__device__ __forceinline__ unsigned short f2bf(float f) {
  union { float f; unsigned int i; } c; c.f = f;
  unsigned int u = c.i;
  u += 0x7FFFu + ((u >> 16) & 1u);   // RNE
  return (unsigned short)(u >> 16);
}
__device__ __forceinline__ float2 ld2(const float* p) { return *(const float2*)p; }
__device__ __forceinline__ bf16x8 pack8(float2 a, float2 b, float2 c, float2 d) {
  union { short s[8]; bf16x8 v; } t;
  t.s[0]=(short)f2bf(a.x); t.s[1]=(short)f2bf(a.y);
  t.s[2]=(short)f2bf(b.x); t.s[3]=(short)f2bf(b.y);
  t.s[4]=(short)f2bf(c.x); t.s[5]=(short)f2bf(c.y);
  t.s[6]=(short)f2bf(d.x); t.s[7]=(short)f2bf(d.y);
  return t.v;
}

__global__ __launch_bounds__(256, 2) void dfl_kernel(
    const float* __restrict__ x,
    const float* __restrict__ Wg,
    const float* __restrict__ Wgb,
    const float* __restrict__ Wh,
    const float* __restrict__ Whb,
    float* __restrict__ out)
{
  // tiny per-wave transpose buffer: 16 rows x 32 cols fp32, XOR-swizzled
  __shared__ __attribute__((aligned(16))) unsigned char tb[4*2048];

  const int tid  = threadIdx.x;
  const int lane = tid & 63;
  const int wv   = tid >> 6;       // 4 waves = 4 col-slabs: g[0:32) g[32:64) h[0:32) h[32:64)
  const int q    = lane >> 4;
  const int l15  = lane & 15;
  const bool is_h = wv >= 2;
  const int colb  = (wv & 1) * 32;
  const float* Wsel  = is_h ? Wh  : Wg;
  const float* Wbsel = is_h ? Whb : Wgb;

  // ---- B-fragment preload (fp32 -> bf16 regs, once per block) ----
  // B-frag 16x16x32: lane holds B[k=(lane>>4)*8+j][n=lane&15] = W[d][f], f contiguous.
  bf16x8 bw[2][KSTEPS];
  float biasf[2], w0f[2];
#pragma unroll
  for (int f = 0; f < 2; ++f) {
    const int dloc = colb + f*16 + l15;                 // 0..63
    const float* wrow = Wsel + (size_t)dloc * FDIM;     // 8B-aligned rows
    biasf[f] = Wbsel[dloc];
    w0f[f]   = wrow[0];
#pragma unroll
    for (int k = 0; k < KSTEPS; ++k) {
      float2 t0 = make_float2(0.f,0.f), t1 = t0, t2 = t0, t3 = t0;
      if (k < 11) {
        const float* p = wrow + k*32 + q*8;
        t0 = ld2(p); t1 = ld2(p+2); t2 = ld2(p+4); t3 = ld2(p+6);
      } else if (q == 0) {
        t0 = ld2(wrow+352); t1 = ld2(wrow+354); t2 = ld2(wrow+356); t3 = ld2(wrow+358);
      } else if (q == 1) {
        t0 = ld2(wrow+360);                              // f=360,361; rest pad 0
      }
      bw[f][k] = pack8(t0, t1, t2, t3);
    }
  }

  unsigned char* wb = tb + wv*2048;
  float* outp = out + (is_h ? OUT_HALF : 0) + colb;

  for (int i = 0; i < TPB; ++i) {
    const int m0  = ((int)blockIdx.x + i*GRID) * TROWS;
    const int row = m0 + l15;
    const float* base = x + (size_t)row * FDIM;

    // partner return value for rank-1 correction (rows m0^512 .. +15)
    float rp = 0.f;
    if (lane < 16) rp = x[(size_t)((m0 ^ 512) + l15) * FDIM];

    // ---- direct global->reg A-fragment loads (all independent, deep MLP) ----
    float2 ar[48];
#pragma unroll
    for (int k = 0; k < 11; ++k) {
      const float* p = base + k*32 + q*8;
      ar[4*k+0] = ld2(p); ar[4*k+1] = ld2(p+2); ar[4*k+2] = ld2(p+4); ar[4*k+3] = ld2(p+6);
    }
    ar[44]=make_float2(0.f,0.f); ar[45]=ar[44]; ar[46]=ar[44]; ar[47]=ar[44];
    if (q == 0) {
      ar[44]=ld2(base+352); ar[45]=ld2(base+354); ar[46]=ld2(base+356); ar[47]=ld2(base+358);
    } else if (q == 1) {
      ar[44]=ld2(base+360);                              // elems 360,361; rest pad 0
    }

    // ---- K-loop: convert + MFMA ----
    f32x4 acc0 = {0.f,0.f,0.f,0.f}, acc1 = acc0;
#pragma unroll
    for (int k = 0; k < KSTEPS; ++k) {
      bf16x8 av = pack8(ar[4*k], ar[4*k+1], ar[4*k+2], ar[4*k+3]);
      acc0 = __builtin_amdgcn_mfma_f32_16x16x32_bf16(av, bw[0][k], acc0, 0,0,0);
      acc1 = __builtin_amdgcn_mfma_f32_16x16x32_bf16(av, bw[1][k], acc1, 0,0,0);
    }

    // ---- rank-1 correction coefficient (valid in lanes 0-15; shfl below) ----
    const float rs = ar[0].x;                            // x[row][0] (q==0 lanes)
    const float cval = is_h ? -(rs + rp)*0.5f : (rp - rs)*0.5f;

    // ---- epilogue: bias + correction, transpose via wave-private LDS ----
#pragma unroll
    for (int jj = 0; jj < 4; ++jj) {
      const float cc = __shfl(cval, q*4 + jj, 64);       // src lanes 0..15
      const int rl = q*4 + jj;                           // C/D row = (lane>>4)*4+reg
#pragma unroll
      for (int fn = 0; fn < 2; ++fn) {
        const float v = (fn ? acc1[jj] : acc0[jj]) + biasf[fn] + cc * w0f[fn];
        const int col = fn*16 + l15;
        const int boff = rl*128 + ((((col>>2) ^ (rl&7))) << 4) + ((col&3) << 2);
        *(float*)(wb + boff) = v;
      }
    }
    // read back row-major: 8 lanes x 16B = full 128B line per output row
#pragma unroll
    for (int s = 0; s < 2; ++s) {
      const int rr = s*8 + (lane >> 3);
      const int cs = lane & 7;
      f32x4 vv = *(const f32x4*)(wb + rr*128 + (((cs ^ (rr&7))) << 4));
      *(f32x4*)(outp + (size_t)(m0 + rr)*64 + cs*4) = vv;
    }

    __builtin_amdgcn_s_barrier();   // keep the 4 waves lockstep for L1 A-reuse
  }
}

extern "C" void kernel_launch(void* const* d_in, const int* in_sizes, int n_in,
                              void* d_out, int out_size, void* d_ws, size_t ws_size,
                              hipStream_t stream) {
  (void)in_sizes; (void)n_in; (void)d_ws; (void)ws_size; (void)out_size;
  const float* x   = (const float*)d_in[0];
  const float* Wg  = (const float*)d_in[1];
  const float* Wgb = (const float*)d_in[2];
  const float* Wh  = (const float*)d_in[3];
  const float* Whb = (const float*)d_in[4];
  float* out = (float*)d_out;
  dfl_kernel<<<GRID, 256, 0, stream>>>(x, Wg, Wgb, Wh, Whb, out);
}